// Round 5
// baseline (413.214 us; speedup 1.0000x reference)
//
#include <hip/hip_runtime.h>
#include <math.h>

#define B_   8
#define NTOK 5376
#define CIN  384
#define CH   768
#define M_   (B_*NTOK)   // 43008

typedef unsigned short u16;
typedef unsigned int   u32;

using bf16x8 = __attribute__((ext_vector_type(8))) short;
using bf16x4 = __attribute__((ext_vector_type(4))) short;
using bf16x2 = __attribute__((ext_vector_type(2))) short;
using f32x4  = __attribute__((ext_vector_type(4))) float;

__device__ __forceinline__ u16 f2bf(float f) {
    union { float f; u32 u; } v; v.f = f;
    u32 r = v.u + 0x7fffu + ((v.u >> 16) & 1u);   // RNE (finite inputs)
    return (u16)(r >> 16);
}
__device__ __forceinline__ float bf2f(u16 u) {
    union { u32 u; float f; } v; v.u = ((u32)u) << 16;
    return v.f;
}
// monotonic order-preserving f32 <-> u32 key (for atomicMax); key(any real) > 0
__device__ __forceinline__ u32 fkey(float f) {
    union { float f; u32 u; } v; v.f = f;
    return (v.u & 0x80000000u) ? ~v.u : (v.u | 0x80000000u);
}
__device__ __forceinline__ float fkeyinv(u32 k) {
    union { u32 u; float f; } v;
    v.u = (k & 0x80000000u) ? (k ^ 0x80000000u) : ~k;
    return v.f;
}
__device__ __forceinline__ float gelu_exact(float f) {
    return 0.5f * f * (1.f + erff(f * 0.70710678118654752f));
}

// ---------------------------------------------------------------- converts
// src: (K, N) f32 row-major  ->  dst: (N, K) bf16 row-major
__global__ void k_cvt_wT(const float* __restrict__ w, u16* __restrict__ wT, int K, int N) {
    int i = blockIdx.x * blockDim.x + threadIdx.x;
    if (i >= N * K) return;
    int n = i / K, k = i % K;
    wT[i] = f2bf(w[k * N + n]);
}

// ---------------------------------------------------------------- fused GEMM
// C[M,N] = f(A)[M,K] @ Bt[N,K]^T + bias.
// B staged via global_load_lds; A reg-staged with an in-flight transform:
//   AM==0 (A_CVT_F32):    A is f32, convert to bf16 during staging (fc1 + x-convert fused)
//   AM==1 (A_SCALE_GELU): A is bf16 xs, apply per-(block-uniform scale row) * GELU (fc2 + apply fused)
#define BM 128
#define BN 128
#define BK 64

template<int AM, bool OUT_BF16>
__launch_bounds__(256)
__global__ void gemm_fused(const void* __restrict__ Asrc, const u16* __restrict__ Bt,
                           const float* __restrict__ bias, const float* __restrict__ scale_all,
                           void* __restrict__ Cout, int M, int N, int K) {
    __shared__ __align__(16) u16 sA[BM * BK];
    __shared__ __align__(16) u16 sB[BN * BK];
    const int mt = blockIdx.x, nt = blockIdx.y;
    const int tid = threadIdx.x;
    const int wave = tid >> 6, lane = tid & 63;
    const int wm = wave >> 1, wn = wave & 1;
    const int row0 = mt * BM, col0 = nt * BN;
    const int lr = lane & 15, lk = lane >> 4;

    // block-uniform scale row (M-tiles never straddle a (b, scale-seg) boundary)
    const float* srow = scale_all;
    if (AM == 1) {
        int b  = row0 / NTOK;
        int t0 = row0 - b * NTOK;
        int s  = (t0 < 4096) ? 0 : (t0 < 5120 ? 1 : 2);
        srow = scale_all + ((size_t)(s * 8 + b)) * CH;
    }

    f32x4 acc[4][4];
#pragma unroll
    for (int m = 0; m < 4; m++)
#pragma unroll
        for (int n = 0; n < 4; n++) acc[m][n] = (f32x4){0.f, 0.f, 0.f, 0.f};

    const int KT = K / BK;
    for (int kt = 0; kt < KT; ++kt) {
        const int k0 = kt * BK;
        // ---- B tile: async DMA to LDS (1024 granules of 16B)
#pragma unroll
        for (int it = 0; it < 4; ++it) {
            int g  = it * 256 + tid;
            int r  = g >> 3;
            int ks = g & 7;
            const u16* gB = Bt + (size_t)(col0 + r) * K + k0 + ks * 8;
            u16* lB = sB + (size_t)(it * 256 + wave * 64) * 8;   // wave-uniform base
            __builtin_amdgcn_global_load_lds(
                (const __attribute__((address_space(1))) u32*)(const void*)gB,
                (__attribute__((address_space(3))) u32*)(void*)lB, 16, 0, 0);
        }
        // ---- A tile: reg-stage + transform + ds_write (overlaps with B DMA)
#pragma unroll
        for (int it = 0; it < 4; ++it) {
            int g  = it * 256 + tid;
            int r  = g >> 3;
            int ks = g & 7;
            bf16x8 o;
            if (AM == 0) {
                const float* ga = (const float*)Asrc + (size_t)(row0 + r) * K + k0 + ks * 8;
                float4 a0 = ((const float4*)ga)[0];
                float4 a1 = ((const float4*)ga)[1];
                o[0] = (short)f2bf(a0.x); o[1] = (short)f2bf(a0.y);
                o[2] = (short)f2bf(a0.z); o[3] = (short)f2bf(a0.w);
                o[4] = (short)f2bf(a1.x); o[5] = (short)f2bf(a1.y);
                o[6] = (short)f2bf(a1.z); o[7] = (short)f2bf(a1.w);
            } else {
                const u16* ga = (const u16*)Asrc + (size_t)(row0 + r) * K + k0 + ks * 8;
                bf16x8 v = *(const bf16x8*)ga;
                const float4* sp = (const float4*)&srow[k0 + ks * 8];
                float4 s0 = sp[0], s1 = sp[1];
                float scv[8] = {s0.x, s0.y, s0.z, s0.w, s1.x, s1.y, s1.z, s1.w};
#pragma unroll
                for (int j = 0; j < 8; j++) {
                    float f = bf2f((u16)v[j]) * scv[j];
                    o[j] = (short)f2bf(gelu_exact(f));
                }
            }
            *(bf16x8*)&sA[(size_t)g * 8] = o;
        }
        __syncthreads();   // drains lgkm (A ds_write) + vm (B DMA)
#pragma unroll
        for (int kk = 0; kk < 2; ++kk) {
            bf16x8 af[4], bfr[4];
#pragma unroll
            for (int m = 0; m < 4; m++)
                af[m] = *(const bf16x8*)&sA[(wm * 64 + m * 16 + lr) * BK + kk * 32 + lk * 8];
#pragma unroll
            for (int n = 0; n < 4; n++)
                bfr[n] = *(const bf16x8*)&sB[(wn * 64 + n * 16 + lr) * BK + kk * 32 + lk * 8];
#pragma unroll
            for (int m = 0; m < 4; m++)
#pragma unroll
                for (int n = 0; n < 4; n++)
                    acc[m][n] = __builtin_amdgcn_mfma_f32_16x16x32_bf16(af[m], bfr[n], acc[m][n], 0, 0, 0);
        }
        __syncthreads();
    }

#pragma unroll
    for (int m = 0; m < 4; m++) {
#pragma unroll
        for (int n = 0; n < 4; n++) {
            int col = col0 + wn * 64 + n * 16 + lr;
            float bv = bias[col];
#pragma unroll
            for (int r = 0; r < 4; r++) {
                int row = row0 + wm * 64 + m * 16 + lk * 4 + r;
                float v = acc[m][n][r] + bv;
                if (OUT_BF16)
                    ((u16*)Cout)[(size_t)row * N + col] = f2bf(v);
                else
                    ((float*)Cout)[(size_t)row * N + col] = v;
            }
        }
    }
}

// ---------------------------------------------------------------- conv pass
// 2-D tiled: one block per (tile, b); tile = 8x8 positions, 384 threads = 384
// channel-pairs (2 ch/thread to keep VGPR low -> higher occupancy).
// 3-row circular register window (compile-time slots), fully unrolled.
// Stats accumulated straight into [3][8][768] via atomics.
// tiles: 0..63 -> s0 (8x8 grid), 64..79 -> s1 (4x4), 80..83 -> s2 (2x2)
__launch_bounds__(384)
__global__ void k_conv(const u16* __restrict__ h, const float* __restrict__ dw_w,
                       const float* __restrict__ dw_b, u16* __restrict__ xs,
                       float* __restrict__ psum, u32* __restrict__ pmaxk) {
    const int tile = blockIdx.x, b = blockIdx.y;
    int s, xt, yt, tokbase, LW;
    if (tile < 64)      { s = 0; xt = tile & 7;  yt = tile >> 3; tokbase = 0;    LW = 6; }
    else if (tile < 80) { int u = tile - 64; s = 1; xt = u & 3; yt = u >> 2; tokbase = 4096; LW = 5; }
    else                { int u = tile - 80; s = 2; xt = u & 1; yt = u >> 1; tokbase = 5120; LW = 4; }
    const int W = 1 << LW, H = W;
    const int x0 = xt * 8, y0 = yt * 8;
    const int c0 = threadIdx.x * 2;

    float wv[9][2], dwb[2];
#pragma unroll
    for (int j = 0; j < 2; j++) {
        dwb[j] = dw_b[c0 + j];
#pragma unroll
        for (int t = 0; t < 9; t++) wv[t][j] = dw_w[(c0 + j) * 9 + t];
    }

    const size_t base = ((size_t)(b * NTOK + tokbase)) * CH + c0;
    const bf16x2 z2 = (bf16x2){0, 0};
    bool colv[10];
    int coloff[10];
#pragma unroll
    for (int j = 0; j < 10; j++) {
        int xx = x0 - 1 + j;
        colv[j] = (xx >= 0) && (xx < W);
        coloff[j] = xx * CH;
    }

    bf16x2 r[3][10];

#define LOADROW(slot, yrow) {                                                   \
        int yr_ = (yrow);                                                       \
        bool rv_ = ((unsigned)yr_ < (unsigned)H);                               \
        int rb_ = yr_ * W * CH;                                                 \
        _Pragma("unroll")                                                       \
        for (int j = 0; j < 10; j++)                                            \
            r[slot][j] = (rv_ && colv[j]) ? *(const bf16x2*)&h[base + rb_ + coloff[j]] : z2; \
    }

    LOADROW(0, y0 - 1);
    LOADROW(1, y0);

    float as[2] = {0.f, 0.f};
    float am[2] = {-3.4e38f, -3.4e38f};

#pragma unroll
    for (int yy = 0; yy < 8; ++yy) {
        const int sm1 = yy % 3, sc = (yy + 1) % 3, sp1 = (yy + 2) % 3;
        LOADROW(sp1, y0 + yy + 1);
        const int orow = (y0 + yy) * W * CH;
#pragma unroll
        for (int p = 0; p < 8; ++p) {
            float o[2];
#pragma unroll
            for (int j = 0; j < 2; j++) o[j] = dwb[j];
#pragma unroll
            for (int kx = 0; kx < 3; ++kx) {
                const int ci = p + kx;
#pragma unroll
                for (int j = 0; j < 2; j++) {
                    o[j] += wv[0 + kx][j] * bf2f((u16)r[sm1][ci][j]);
                    o[j] += wv[3 + kx][j] * bf2f((u16)r[sc ][ci][j]);
                    o[j] += wv[6 + kx][j] * bf2f((u16)r[sp1][ci][j]);
                }
            }
            bf16x2 ov;
#pragma unroll
            for (int j = 0; j < 2; j++) {
                ov[j] = (short)f2bf(o[j]);
                as[j] += o[j];
                am[j] = fmaxf(am[j], o[j]);
            }
            *(bf16x2*)&xs[base + orow + (x0 + p) * CH] = ov;
        }
    }
#undef LOADROW

#pragma unroll
    for (int j = 0; j < 2; j++) {
        atomicAdd(&psum[(s * 8 + b) * CH + c0 + j], as[j]);
        atomicMax(&pmaxk[(s * 8 + b) * CH + c0 + j], fkey(am[j]));
    }
}

// gate softmax + channel conv1 gates + blended scale. grid (3, 8)
__global__ void k_scale(const float* __restrict__ psum, const u32* __restrict__ pmaxk,
                        const float* __restrict__ gate_w, const float* __restrict__ gate_b,
                        const float* __restrict__ ca_w, const float* __restrict__ ra_w,
                        float* __restrict__ scale) {
    int s = blockIdx.x, b = blockIdx.y;
    int tid = threadIdx.x;
    float npos = (s == 0) ? 4096.f : (s == 1) ? 1024.f : 256.f;
    __shared__ float pooled[CH];
    __shared__ float rl[4][2];
    float l0 = 0.f, l1 = 0.f;
#pragma unroll
    for (int j = 0; j < 3; j++) {
        int c = j * 256 + tid;
        size_t idx = ((size_t)s * 8 + b) * CH + c;
        float avg = psum[idx] / npos;
        float mxv = fkeyinv(pmaxk[idx]);
        pooled[c] = avg + mxv;
        l0 += avg * gate_w[c * 2 + 0];
        l1 += avg * gate_w[c * 2 + 1];
    }
    for (int off = 32; off; off >>= 1) {
        l0 += __shfl_down(l0, off);
        l1 += __shfl_down(l1, off);
    }
    int wave = tid >> 6, lane = tid & 63;
    if (lane == 0) { rl[wave][0] = l0; rl[wave][1] = l1; }
    __syncthreads();
    float L0 = rl[0][0] + rl[1][0] + rl[2][0] + rl[3][0] + gate_b[0];
    float L1 = rl[0][1] + rl[1][1] + rl[2][1] + rl[3][1] + gate_b[1];
    float mxl = fmaxf(L0, L1);
    float e0 = expf(L0 - mxl), e1 = expf(L1 - mxl);
    float g0 = e0 / (e0 + e1), g1 = e1 / (e0 + e1);
    float cw0 = ca_w[0], cw1 = ca_w[1], cw2 = ca_w[2];
    float rw0 = ra_w[0], rw1 = ra_w[1], rw2 = ra_w[2];
#pragma unroll
    for (int j = 0; j < 3; j++) {
        int c = j * 256 + tid;
        float pm = (c > 0)      ? pooled[c - 1] : 0.f;
        float pc = pooled[c];
        float pp = (c < CH - 1) ? pooled[c + 1] : 0.f;
        float cas = 1.f / (1.f + expf(-(cw0 * pm + cw1 * pc + cw2 * pp)));
        float ras = 1.f - 1.f / (1.f + expf(-(rw0 * pm + rw1 * pc + rw2 * pp)));
        scale[((size_t)s * 8 + b) * CH + c] = g0 * cas + g1 * ras;
    }
}

// ---------------------------------------------------------------- launch
extern "C" void kernel_launch(void* const* d_in, const int* in_sizes, int n_in,
                              void* d_out, int out_size, void* d_ws, size_t ws_size,
                              hipStream_t stream) {
    const float* x      = (const float*)d_in[0];
    const float* fc1_w  = (const float*)d_in[1];
    const float* fc1_b  = (const float*)d_in[2];
    const float* dw_w   = (const float*)d_in[3];
    const float* dw_b   = (const float*)d_in[4];
    const float* ca_w   = (const float*)d_in[5];
    const float* ra_w   = (const float*)d_in[6];
    const float* gate_w = (const float*)d_in[7];
    const float* gate_b = (const float*)d_in[8];
    const float* fc2_w  = (const float*)d_in[9];
    const float* fc2_b  = (const float*)d_in[10];

    char* ws = (char*)d_ws;
    u16*  hb    = (u16*)(ws);                    // 43008*768*2  = 66,060,288
    u16*  xs    = (u16*)(ws + 66060288);         // 43008*768*2  = 66,060,288
    u16*  w1T   = (u16*)(ws + 132120576);        // 768*384*2    =    589,824
    u16*  w2T   = (u16*)(ws + 132710400);        // 384*768*2    =    589,824
    float* psum = (float*)(ws + 133300224);      // 3*8*768*4    =     73,728
    u32*  pmaxk = (u32*)(ws + 133373952);        // 3*8*768*4    =     73,728
    float* scale= (float*)(ws + 133447680);      // 3*8*768*4    =     73,728

    // 0) zero the atomic accumulators (psum=0; pmaxk key 0 < key(any real))
    hipMemsetAsync((void*)psum, 0, 147456, stream);

    // 1) weight transpose+convert (1.2 MB total)
    k_cvt_wT<<<(CIN * CH + 255) / 256, 256, 0, stream>>>(fc1_w, w1T, CIN, CH);
    k_cvt_wT<<<(CIN * CH + 255) / 256, 256, 0, stream>>>(fc2_w, w2T, CH, CIN);

    // 2) fc1 (f32->bf16 convert fused into A staging): x @ fc1_w -> h bf16
    gemm_fused<0, true><<<dim3(M_ / BM, CH / BN), 256, 0, stream>>>(
        (const void*)x, w1T, fc1_b, nullptr, (void*)hb, M_, CH, CIN);

    // 3) depthwise conv (2-D tiled register window) -> xs + atomic stats
    k_conv<<<dim3(84, 8), 384, 0, stream>>>(hb, dw_w, dw_b, xs, psum, pmaxk);

    // 4) per-(scale,b) gate/scale computation
    k_scale<<<dim3(3, 8), 256, 0, stream>>>(psum, pmaxk, gate_w, gate_b, ca_w, ra_w, scale);

    // 5) fc2 (scale + exact-GELU fused into A staging): GELU(xs*scale) @ fc2_w + bias -> out f32
    gemm_fused<1, false><<<dim3(M_ / BM, CIN / BN), 256, 0, stream>>>(
        (const void*)xs, w2T, fc2_b, scale, d_out, M_, CIN, CH);
}

// Round 6
// 365.152 us; speedup vs baseline: 1.1316x; 1.1316x over previous
//
#include <hip/hip_runtime.h>
#include <hip/hip_bf16.h>
#include <math.h>

#define B_   8
#define NTOK 5376
#define CIN  384
#define CH   768
#define M_   (B_*NTOK)   // 43008

typedef unsigned short u16;
typedef unsigned int   u32;

using bf16x8 = __attribute__((ext_vector_type(8))) short;
using bf16x2 = __attribute__((ext_vector_type(2))) short;
using f32x4  = __attribute__((ext_vector_type(4))) float;

__device__ __forceinline__ u16 f2bf(float f) {
    union { float f; u32 u; } v; v.f = f;
    u32 r = v.u + 0x7fffu + ((v.u >> 16) & 1u);   // RNE (finite inputs)
    return (u16)(r >> 16);
}
__device__ __forceinline__ float bf2f(u16 u) {
    union { u32 u; float f; } v; v.u = ((u32)u) << 16;
    return v.f;
}
// monotonic order-preserving f32 <-> u32 key (for atomicMax); key(any real) > 0
__device__ __forceinline__ u32 fkey(float f) {
    union { float f; u32 u; } v; v.f = f;
    return (v.u & 0x80000000u) ? ~v.u : (v.u | 0x80000000u);
}
__device__ __forceinline__ float fkeyinv(u32 k) {
    union { u32 u; float f; } v;
    v.u = (k & 0x80000000u) ? (k ^ 0x80000000u) : ~k;
    return v.f;
}
__device__ __forceinline__ float gelu_exact(float f) {
    return 0.5f * f * (1.f + erff(f * 0.70710678118654752f));
}

// ---------------------------------------------------------------- converts
// src: (K, N) f32 row-major  ->  dst: (N, K) bf16 row-major
__global__ void k_cvt_wT(const float* __restrict__ w, u16* __restrict__ wT, int K, int N) {
    int i = blockIdx.x * blockDim.x + threadIdx.x;
    if (i >= N * K) return;
    int n = i / K, k = i % K;
    wT[i] = f2bf(w[k * N + n]);
}

// ---------------------------------------------------------------- GEMM
// C[M,N] = A[M,K] @ Bt[N,K]^T + bias.
//   AM==0: A is f32 -> reg-stage + v_cvt_pk_bf16_f32 convert + ds_write (fc1)
//   AM==2: A is bf16 -> global_load_lds DMA like B (fc2)
#define BM 128
#define BN 128
#define BK 64

template<int AM, bool OUT_BF16>
__launch_bounds__(256)
__global__ void gemm_fused(const void* __restrict__ Asrc, const u16* __restrict__ Bt,
                           const float* __restrict__ bias, void* __restrict__ Cout,
                           int M, int N, int K) {
    __shared__ __align__(16) u16 sA[BM * BK];
    __shared__ __align__(16) u16 sB[BN * BK];
    const int mt = blockIdx.x, nt = blockIdx.y;
    const int tid = threadIdx.x;
    const int wave = tid >> 6, lane = tid & 63;
    const int wm = wave >> 1, wn = wave & 1;
    const int row0 = mt * BM, col0 = nt * BN;
    const int lr = lane & 15, lk = lane >> 4;

    f32x4 acc[4][4];
#pragma unroll
    for (int m = 0; m < 4; m++)
#pragma unroll
        for (int n = 0; n < 4; n++) acc[m][n] = (f32x4){0.f, 0.f, 0.f, 0.f};

    const int KT = K / BK;
    for (int kt = 0; kt < KT; ++kt) {
        const int k0 = kt * BK;
        // ---- B tile (and A tile if AM==2): async DMA to LDS
#pragma unroll
        for (int it = 0; it < 4; ++it) {
            int g  = it * 256 + tid;
            int r  = g >> 3;
            int ks = g & 7;
            const u16* gB = Bt + (size_t)(col0 + r) * K + k0 + ks * 8;
            u16* lB = sB + (size_t)(it * 256 + wave * 64) * 8;   // wave-uniform base
            __builtin_amdgcn_global_load_lds(
                (const __attribute__((address_space(1))) u32*)(const void*)gB,
                (__attribute__((address_space(3))) u32*)(void*)lB, 16, 0, 0);
            if (AM == 2) {
                const u16* gA = (const u16*)Asrc + (size_t)(row0 + r) * K + k0 + ks * 8;
                u16* lA = sA + (size_t)(it * 256 + wave * 64) * 8;
                __builtin_amdgcn_global_load_lds(
                    (const __attribute__((address_space(1))) u32*)(const void*)gA,
                    (__attribute__((address_space(3))) u32*)(void*)lA, 16, 0, 0);
            }
        }
        // ---- A tile for AM==0: reg-stage f32 + packed convert + ds_write
        if (AM == 0) {
#pragma unroll
            for (int it = 0; it < 4; ++it) {
                int g  = it * 256 + tid;
                int r  = g >> 3;
                int ks = g & 7;
                const float* ga = (const float*)Asrc + (size_t)(row0 + r) * K + k0 + ks * 8;
                float4 a0 = ((const float4*)ga)[0];
                float4 a1 = ((const float4*)ga)[1];
                union { __hip_bfloat162 h2[4]; bf16x8 v; } o;
                o.h2[0] = __float22bfloat162_rn({a0.x, a0.y});   // v_cvt_pk_bf16_f32
                o.h2[1] = __float22bfloat162_rn({a0.z, a0.w});
                o.h2[2] = __float22bfloat162_rn({a1.x, a1.y});
                o.h2[3] = __float22bfloat162_rn({a1.z, a1.w});
                *(bf16x8*)&sA[(size_t)g * 8] = o.v;
            }
        }
        __syncthreads();   // drains lgkm (A ds_write) + vm (DMA)
#pragma unroll
        for (int kk = 0; kk < 2; ++kk) {
            bf16x8 af[4], bfr[4];
#pragma unroll
            for (int m = 0; m < 4; m++)
                af[m] = *(const bf16x8*)&sA[(wm * 64 + m * 16 + lr) * BK + kk * 32 + lk * 8];
#pragma unroll
            for (int n = 0; n < 4; n++)
                bfr[n] = *(const bf16x8*)&sB[(wn * 64 + n * 16 + lr) * BK + kk * 32 + lk * 8];
#pragma unroll
            for (int m = 0; m < 4; m++)
#pragma unroll
                for (int n = 0; n < 4; n++)
                    acc[m][n] = __builtin_amdgcn_mfma_f32_16x16x32_bf16(af[m], bfr[n], acc[m][n], 0, 0, 0);
        }
        __syncthreads();
    }

#pragma unroll
    for (int m = 0; m < 4; m++) {
#pragma unroll
        for (int n = 0; n < 4; n++) {
            int col = col0 + wn * 64 + n * 16 + lr;
            float bv = bias[col];
#pragma unroll
            for (int r = 0; r < 4; r++) {
                int row = row0 + wm * 64 + m * 16 + lk * 4 + r;
                float v = acc[m][n][r] + bv;
                if (OUT_BF16)
                    ((u16*)Cout)[(size_t)row * N + col] = f2bf(v);
                else
                    ((float*)Cout)[(size_t)row * N + col] = v;
            }
        }
    }
}

// ---------------------------------------------------------------- conv pass
// 2-D tiled: one block per (tile, b); tile = 8x8 positions, 384 threads = 384
// channel-pairs (2 ch/thread keeps VGPR low -> higher occupancy).
// tiles: 0..63 -> s0 (8x8 grid), 64..79 -> s1 (4x4), 80..83 -> s2 (2x2)
__launch_bounds__(384)
__global__ void k_conv(const u16* __restrict__ h, const float* __restrict__ dw_w,
                       const float* __restrict__ dw_b, u16* __restrict__ xs,
                       float* __restrict__ psum, u32* __restrict__ pmaxk) {
    const int tile = blockIdx.x, b = blockIdx.y;
    int s, xt, yt, tokbase, LW;
    if (tile < 64)      { s = 0; xt = tile & 7;  yt = tile >> 3; tokbase = 0;    LW = 6; }
    else if (tile < 80) { int u = tile - 64; s = 1; xt = u & 3; yt = u >> 2; tokbase = 4096; LW = 5; }
    else                { int u = tile - 80; s = 2; xt = u & 1; yt = u >> 1; tokbase = 5120; LW = 4; }
    const int W = 1 << LW, H = W;
    const int x0 = xt * 8, y0 = yt * 8;
    const int c0 = threadIdx.x * 2;

    float wv[9][2], dwb[2];
#pragma unroll
    for (int j = 0; j < 2; j++) {
        dwb[j] = dw_b[c0 + j];
#pragma unroll
        for (int t = 0; t < 9; t++) wv[t][j] = dw_w[(c0 + j) * 9 + t];
    }

    const size_t base = ((size_t)(b * NTOK + tokbase)) * CH + c0;
    const bf16x2 z2 = (bf16x2){0, 0};
    bool colv[10];
    int coloff[10];
#pragma unroll
    for (int j = 0; j < 10; j++) {
        int xx = x0 - 1 + j;
        colv[j] = (xx >= 0) && (xx < W);
        coloff[j] = xx * CH;
    }

    bf16x2 r[3][10];

#define LOADROW(slot, yrow) {                                                   \
        int yr_ = (yrow);                                                       \
        bool rv_ = ((unsigned)yr_ < (unsigned)H);                               \
        int rb_ = yr_ * W * CH;                                                 \
        _Pragma("unroll")                                                       \
        for (int j = 0; j < 10; j++)                                            \
            r[slot][j] = (rv_ && colv[j]) ? *(const bf16x2*)&h[base + rb_ + coloff[j]] : z2; \
    }

    LOADROW(0, y0 - 1);
    LOADROW(1, y0);

    float as[2] = {0.f, 0.f};
    float am[2] = {-3.4e38f, -3.4e38f};

#pragma unroll
    for (int yy = 0; yy < 8; ++yy) {
        const int sm1 = yy % 3, sc = (yy + 1) % 3, sp1 = (yy + 2) % 3;
        LOADROW(sp1, y0 + yy + 1);
        const int orow = (y0 + yy) * W * CH;
#pragma unroll
        for (int p = 0; p < 8; ++p) {
            float o[2];
#pragma unroll
            for (int j = 0; j < 2; j++) o[j] = dwb[j];
#pragma unroll
            for (int kx = 0; kx < 3; ++kx) {
                const int ci = p + kx;
#pragma unroll
                for (int j = 0; j < 2; j++) {
                    o[j] += wv[0 + kx][j] * bf2f((u16)r[sm1][ci][j]);
                    o[j] += wv[3 + kx][j] * bf2f((u16)r[sc ][ci][j]);
                    o[j] += wv[6 + kx][j] * bf2f((u16)r[sp1][ci][j]);
                }
            }
            bf16x2 ov;
#pragma unroll
            for (int j = 0; j < 2; j++) {
                ov[j] = (short)f2bf(o[j]);
                as[j] += o[j];
                am[j] = fmaxf(am[j], o[j]);
            }
            *(bf16x2*)&xs[base + orow + (x0 + p) * CH] = ov;
        }
    }
#undef LOADROW

#pragma unroll
    for (int j = 0; j < 2; j++) {
        atomicAdd(&psum[(s * 8 + b) * CH + c0 + j], as[j]);
        atomicMax(&pmaxk[(s * 8 + b) * CH + c0 + j], fkey(am[j]));
    }
}

// gate softmax + channel conv1 gates + blended scale. grid (3, 8)
__global__ void k_scale(const float* __restrict__ psum, const u32* __restrict__ pmaxk,
                        const float* __restrict__ gate_w, const float* __restrict__ gate_b,
                        const float* __restrict__ ca_w, const float* __restrict__ ra_w,
                        float* __restrict__ scale) {
    int s = blockIdx.x, b = blockIdx.y;
    int tid = threadIdx.x;
    float npos = (s == 0) ? 4096.f : (s == 1) ? 1024.f : 256.f;
    __shared__ float pooled[CH];
    __shared__ float rl[4][2];
    float l0 = 0.f, l1 = 0.f;
#pragma unroll
    for (int j = 0; j < 3; j++) {
        int c = j * 256 + tid;
        size_t idx = ((size_t)s * 8 + b) * CH + c;
        float avg = psum[idx] / npos;
        float mxv = fkeyinv(pmaxk[idx]);
        pooled[c] = avg + mxv;
        l0 += avg * gate_w[c * 2 + 0];
        l1 += avg * gate_w[c * 2 + 1];
    }
    for (int off = 32; off; off >>= 1) {
        l0 += __shfl_down(l0, off);
        l1 += __shfl_down(l1, off);
    }
    int wave = tid >> 6, lane = tid & 63;
    if (lane == 0) { rl[wave][0] = l0; rl[wave][1] = l1; }
    __syncthreads();
    float L0 = rl[0][0] + rl[1][0] + rl[2][0] + rl[3][0] + gate_b[0];
    float L1 = rl[0][1] + rl[1][1] + rl[2][1] + rl[3][1] + gate_b[1];
    float mxl = fmaxf(L0, L1);
    float e0 = expf(L0 - mxl), e1 = expf(L1 - mxl);
    float g0 = e0 / (e0 + e1), g1 = e1 / (e0 + e1);
    float cw0 = ca_w[0], cw1 = ca_w[1], cw2 = ca_w[2];
    float rw0 = ra_w[0], rw1 = ra_w[1], rw2 = ra_w[2];
#pragma unroll
    for (int j = 0; j < 3; j++) {
        int c = j * 256 + tid;
        float pm = (c > 0)      ? pooled[c - 1] : 0.f;
        float pc = pooled[c];
        float pp = (c < CH - 1) ? pooled[c + 1] : 0.f;
        float cas = 1.f / (1.f + expf(-(cw0 * pm + cw1 * pc + cw2 * pp)));
        float ras = 1.f - 1.f / (1.f + expf(-(rw0 * pm + rw1 * pc + rw2 * pp)));
        scale[((size_t)s * 8 + b) * CH + c] = g0 * cas + g1 * ras;
    }
}

// streaming: xs <- bf16(GELU(xs * scale)) in place. grid-stride over c8-groups.
#define NG (M_ * (CH / 8))
__global__ void k_apply(u16* __restrict__ xs, const float* __restrict__ scale) {
    for (int gi = blockIdx.x * blockDim.x + threadIdx.x; gi < NG;
         gi += gridDim.x * blockDim.x) {
        int c8 = gi % 96;
        int tl = gi / 96;            // b*5376 + t
        int t = tl % NTOK, b = tl / NTOK;
        int s = (t < 4096) ? 0 : (t < 5120 ? 1 : 2);
        const float4* sp = (const float4*)&scale[((size_t)(s * 8 + b)) * CH + c8 * 8];
        float4 sc0 = sp[0], sc1 = sp[1];
        float scv[8] = {sc0.x, sc0.y, sc0.z, sc0.w, sc1.x, sc1.y, sc1.z, sc1.w};
        bf16x8 v = *(const bf16x8*)&xs[(size_t)gi * 8];
        bf16x8 o;
#pragma unroll
        for (int j = 0; j < 8; j++) {
            float f = bf2f((u16)v[j]) * scv[j];
            o[j] = (short)f2bf(gelu_exact(f));
        }
        *(bf16x8*)&xs[(size_t)gi * 8] = o;
    }
}

// ---------------------------------------------------------------- launch
extern "C" void kernel_launch(void* const* d_in, const int* in_sizes, int n_in,
                              void* d_out, int out_size, void* d_ws, size_t ws_size,
                              hipStream_t stream) {
    const float* x      = (const float*)d_in[0];
    const float* fc1_w  = (const float*)d_in[1];
    const float* fc1_b  = (const float*)d_in[2];
    const float* dw_w   = (const float*)d_in[3];
    const float* dw_b   = (const float*)d_in[4];
    const float* ca_w   = (const float*)d_in[5];
    const float* ra_w   = (const float*)d_in[6];
    const float* gate_w = (const float*)d_in[7];
    const float* gate_b = (const float*)d_in[8];
    const float* fc2_w  = (const float*)d_in[9];
    const float* fc2_b  = (const float*)d_in[10];

    char* ws = (char*)d_ws;
    u16*  hb    = (u16*)(ws);                    // 43008*768*2  = 66,060,288
    u16*  xs    = (u16*)(ws + 66060288);         // 43008*768*2  = 66,060,288
    u16*  w1T   = (u16*)(ws + 132120576);        // 768*384*2    =    589,824
    u16*  w2T   = (u16*)(ws + 132710400);        // 384*768*2    =    589,824
    float* psum = (float*)(ws + 133300224);      // 3*8*768*4    =     73,728
    u32*  pmaxk = (u32*)(ws + 133373952);        // 3*8*768*4    =     73,728
    float* scale= (float*)(ws + 133447680);      // 3*8*768*4    =     73,728

    // 0) zero the atomic accumulators (psum=0; pmaxk key 0 < key(any real))
    hipMemsetAsync((void*)psum, 0, 147456, stream);

    // 1) weight transpose+convert (1.2 MB total)
    k_cvt_wT<<<(CIN * CH + 255) / 256, 256, 0, stream>>>(fc1_w, w1T, CIN, CH);
    k_cvt_wT<<<(CIN * CH + 255) / 256, 256, 0, stream>>>(fc2_w, w2T, CH, CIN);

    // 2) fc1 (f32->bf16 packed-convert fused into A staging): x @ fc1_w -> h bf16
    gemm_fused<0, true><<<dim3(M_ / BM, CH / BN), 256, 0, stream>>>(
        (const void*)x, w1T, fc1_b, (void*)hb, M_, CH, CIN);

    // 3) depthwise conv (2-D tiled register window) -> xs + atomic stats
    k_conv<<<dim3(84, 8), 384, 0, stream>>>(hb, dw_w, dw_b, xs, psum, pmaxk);

    // 4) per-(scale,b) gate/scale computation
    k_scale<<<dim3(3, 8), 256, 0, stream>>>(psum, pmaxk, gate_w, gate_b, ca_w, ra_w, scale);

    // 5) streaming scale + exact GELU, in place on xs
    k_apply<<<4096, 256, 0, stream>>>(xs, scale);

    // 6) fc2 (pure DMA staging): GELU'd xs @ fc2_w + bias -> out f32
    gemm_fused<2, false><<<dim3(M_ / BM, CIN / BN), 256, 0, stream>>>(
        (const void*)xs, w2T, fc2_b, d_out, M_, CIN, CH);
}

// Round 7
// 363.427 us; speedup vs baseline: 1.1370x; 1.0047x over previous
//
#include <hip/hip_runtime.h>
#include <hip/hip_bf16.h>
#include <math.h>

#define B_   8
#define NTOK 5376
#define CIN  384
#define CH   768
#define M_   (B_*NTOK)   // 43008

typedef unsigned short u16;
typedef unsigned int   u32;

using bf16x8 = __attribute__((ext_vector_type(8))) short;
using bf16x4 = __attribute__((ext_vector_type(4))) short;
using f32x4  = __attribute__((ext_vector_type(4))) float;

__device__ __forceinline__ u16 f2bf(float f) {
    union { float f; u32 u; } v; v.f = f;
    u32 r = v.u + 0x7fffu + ((v.u >> 16) & 1u);   // RNE (finite inputs)
    return (u16)(r >> 16);
}
__device__ __forceinline__ float bf2f(u16 u) {
    union { u32 u; float f; } v; v.u = ((u32)u) << 16;
    return v.f;
}
// monotonic order-preserving f32 <-> u32 key (for atomicMax); key(any real) > 0
__device__ __forceinline__ u32 fkey(float f) {
    union { float f; u32 u; } v; v.f = f;
    return (v.u & 0x80000000u) ? ~v.u : (v.u | 0x80000000u);
}
__device__ __forceinline__ float fkeyinv(u32 k) {
    union { u32 u; float f; } v;
    v.u = (k & 0x80000000u) ? (k ^ 0x80000000u) : ~k;
    return v.f;
}
__device__ __forceinline__ float gelu_exact(float f) {
    return 0.5f * f * (1.f + erff(f * 0.70710678118654752f));
}

// ---------------------------------------------------------------- converts
// src: (K, N) f32 row-major  ->  dst: (N, K) bf16 row-major
__global__ void k_cvt_wT(const float* __restrict__ w, u16* __restrict__ wT, int K, int N) {
    int i = blockIdx.x * blockDim.x + threadIdx.x;
    if (i >= N * K) return;
    int n = i / K, k = i % K;
    wT[i] = f2bf(w[k * N + n]);
}

// ---------------------------------------------------------------- GEMM
// C[M,N] = A[M,K] @ Bt[N,K]^T + bias, 2-phase double-buffered pipeline:
// per K-iter: issue next tile's loads -> compute current -> (A cvt+ds_write) -> one barrier.
//   AM==0: A is f32 -> reg-load early, v_cvt_pk convert + ds_write after MFMA (fc1)
//   AM==2: A is bf16 -> global_load_lds DMA like B (fc2)
#define BM 128
#define BN 128
#define BK 64

template<int AM, bool OUT_BF16>
__launch_bounds__(256)
__global__ void gemm_fused(const void* __restrict__ Asrc, const u16* __restrict__ Bt,
                           const float* __restrict__ bias, void* __restrict__ Cout,
                           int M, int N, int K) {
    __shared__ __align__(16) u16 sA[2][BM * BK];
    __shared__ __align__(16) u16 sB[2][BN * BK];
    const int mt = blockIdx.x, nt = blockIdx.y;
    const int tid = threadIdx.x;
    const int wave = tid >> 6, lane = tid & 63;
    const int wm = wave >> 1, wn = wave & 1;
    const int row0 = mt * BM, col0 = nt * BN;
    const int lr = lane & 15, lk = lane >> 4;

    f32x4 acc[4][4];
#pragma unroll
    for (int m = 0; m < 4; m++)
#pragma unroll
        for (int n = 0; n < 4; n++) acc[m][n] = (f32x4){0.f, 0.f, 0.f, 0.f};

    float4 a0[4], a1[4];    // AM==0 in-flight A registers

    // issue async DMA for K-tile kt into buffer buf
    auto STAGE_DMA = [&](int buf, int kt) {
        const int k0 = kt * BK;
#pragma unroll
        for (int it = 0; it < 4; ++it) {
            int g  = it * 256 + tid;
            int r  = g >> 3;
            int ks = g & 7;
            const u16* gB = Bt + (size_t)(col0 + r) * K + k0 + ks * 8;
            u16* lB = sB[buf] + (size_t)(it * 256 + wave * 64) * 8;   // wave-uniform base
            __builtin_amdgcn_global_load_lds(
                (const __attribute__((address_space(1))) u32*)(const void*)gB,
                (__attribute__((address_space(3))) u32*)(void*)lB, 16, 0, 0);
            if (AM == 2) {
                const u16* gA = (const u16*)Asrc + (size_t)(row0 + r) * K + k0 + ks * 8;
                u16* lA = sA[buf] + (size_t)(it * 256 + wave * 64) * 8;
                __builtin_amdgcn_global_load_lds(
                    (const __attribute__((address_space(1))) u32*)(const void*)gA,
                    (__attribute__((address_space(3))) u32*)(void*)lA, 16, 0, 0);
            }
        }
    };
    // AM==0: issue f32 A loads for K-tile kt into regs
    auto ALOAD = [&](int kt) {
        const int k0 = kt * BK;
#pragma unroll
        for (int it = 0; it < 4; ++it) {
            int g  = it * 256 + tid;
            int r  = g >> 3;
            int ks = g & 7;
            const float* ga = (const float*)Asrc + (size_t)(row0 + r) * K + k0 + ks * 8;
            a0[it] = ((const float4*)ga)[0];
            a1[it] = ((const float4*)ga)[1];
        }
    };
    // AM==0: convert + ds_write the in-flight A regs into buffer buf
    auto ASTORE = [&](int buf) {
#pragma unroll
        for (int it = 0; it < 4; ++it) {
            int g = it * 256 + tid;
            union { __hip_bfloat162 h2[4]; bf16x8 v; } o;
            o.h2[0] = __float22bfloat162_rn({a0[it].x, a0[it].y});   // v_cvt_pk_bf16_f32
            o.h2[1] = __float22bfloat162_rn({a0[it].z, a0[it].w});
            o.h2[2] = __float22bfloat162_rn({a1[it].x, a1[it].y});
            o.h2[3] = __float22bfloat162_rn({a1[it].z, a1[it].w});
            *(bf16x8*)&sA[buf][(size_t)g * 8] = o.v;
        }
    };

    // prologue: stage tile 0
    STAGE_DMA(0, 0);
    if (AM == 0) { ALOAD(0); ASTORE(0); }
    __syncthreads();

    const int KT = K / BK;
    int cur = 0;
    for (int kt = 0; kt < KT; ++kt) {
        const int nxt = cur ^ 1;
        const bool more = (kt + 1 < KT);
        if (more) {
            if (AM == 0) ALOAD(kt + 1);   // async f32 loads, consumed after MFMA
            STAGE_DMA(nxt, kt + 1);       // async DMA, drained at barrier
        }
        // compute current tile
#pragma unroll
        for (int kk = 0; kk < 2; ++kk) {
            bf16x8 af[4], bfr[4];
#pragma unroll
            for (int m = 0; m < 4; m++)
                af[m] = *(const bf16x8*)&sA[cur][(wm * 64 + m * 16 + lr) * BK + kk * 32 + lk * 8];
#pragma unroll
            for (int n = 0; n < 4; n++)
                bfr[n] = *(const bf16x8*)&sB[cur][(wn * 64 + n * 16 + lr) * BK + kk * 32 + lk * 8];
#pragma unroll
            for (int m = 0; m < 4; m++)
#pragma unroll
                for (int n = 0; n < 4; n++)
                    acc[m][n] = __builtin_amdgcn_mfma_f32_16x16x32_bf16(af[m], bfr[n], acc[m][n], 0, 0, 0);
        }
        if (more && AM == 0) ASTORE(nxt);   // vmcnt wait lands here, after MFMA
        __syncthreads();                     // one drain+barrier per K-iter
        cur = nxt;
    }

#pragma unroll
    for (int m = 0; m < 4; m++) {
#pragma unroll
        for (int n = 0; n < 4; n++) {
            int col = col0 + wn * 64 + n * 16 + lr;
            float bv = bias[col];
#pragma unroll
            for (int r = 0; r < 4; r++) {
                int row = row0 + wm * 64 + m * 16 + lk * 4 + r;
                float v = acc[m][n][r] + bv;
                if (OUT_BF16)
                    ((u16*)Cout)[(size_t)row * N + col] = f2bf(v);
                else
                    ((float*)Cout)[(size_t)row * N + col] = v;
            }
        }
    }
}

// ---------------------------------------------------------------- conv pass
// One block per (tile, b); tile = 4x8 positions (x-range 4, y-range 8).
// 192 threads = 192 channel-quads, 8B bf16x4 loads (load width > wave count).
// 3-row x 6-col circular register window, fully unrolled.
// tiles: 0..127 -> s0 (16x8 grid), 128..159 -> s1 (8x4), 160..167 -> s2 (4x2)
__launch_bounds__(192, 3)
__global__ void k_conv(const u16* __restrict__ h, const float* __restrict__ dw_w,
                       const float* __restrict__ dw_b, u16* __restrict__ xs,
                       float* __restrict__ psum, u32* __restrict__ pmaxk) {
    const int tile = blockIdx.x, b = blockIdx.y;
    int s, xt, yt, tokbase, LW;
    if (tile < 128)      { s = 0; xt = tile & 15; yt = tile >> 4; tokbase = 0;    LW = 6; }
    else if (tile < 160) { int u = tile - 128; s = 1; xt = u & 7; yt = u >> 3; tokbase = 4096; LW = 5; }
    else                 { int u = tile - 160; s = 2; xt = u & 3; yt = u >> 2; tokbase = 5120; LW = 4; }
    const int W = 1 << LW, H = W;
    const int x0 = xt * 4, y0 = yt * 8;
    const int c0 = threadIdx.x * 4;

    float wv[9][4], dwb[4];
#pragma unroll
    for (int j = 0; j < 4; j++) {
        dwb[j] = dw_b[c0 + j];
#pragma unroll
        for (int t = 0; t < 9; t++) wv[t][j] = dw_w[(c0 + j) * 9 + t];
    }

    const size_t base = ((size_t)(b * NTOK + tokbase)) * CH + c0;
    const bf16x4 z4 = (bf16x4){0, 0, 0, 0};
    bool colv[6];
    int coloff[6];
#pragma unroll
    for (int j = 0; j < 6; j++) {
        int xx = x0 - 1 + j;
        colv[j] = (xx >= 0) && (xx < W);
        coloff[j] = xx * CH;
    }

    bf16x4 r[3][6];

#define LOADROW(slot, yrow) {                                                   \
        int yr_ = (yrow);                                                       \
        bool rv_ = ((unsigned)yr_ < (unsigned)H);                               \
        int rb_ = yr_ * W * CH;                                                 \
        _Pragma("unroll")                                                       \
        for (int j = 0; j < 6; j++)                                             \
            r[slot][j] = (rv_ && colv[j]) ? *(const bf16x4*)&h[base + rb_ + coloff[j]] : z4; \
    }

    LOADROW(0, y0 - 1);
    LOADROW(1, y0);

    float as[4] = {0.f, 0.f, 0.f, 0.f};
    float am[4] = {-3.4e38f, -3.4e38f, -3.4e38f, -3.4e38f};

#pragma unroll
    for (int yy = 0; yy < 8; ++yy) {
        const int sm1 = yy % 3, sc = (yy + 1) % 3, sp1 = (yy + 2) % 3;
        LOADROW(sp1, y0 + yy + 1);
        const int orow = (y0 + yy) * W * CH;
#pragma unroll
        for (int p = 0; p < 4; ++p) {
            float o[4];
#pragma unroll
            for (int j = 0; j < 4; j++) o[j] = dwb[j];
#pragma unroll
            for (int kx = 0; kx < 3; ++kx) {
                const int ci = p + kx;
#pragma unroll
                for (int j = 0; j < 4; j++) {
                    o[j] += wv[0 + kx][j] * bf2f((u16)r[sm1][ci][j]);
                    o[j] += wv[3 + kx][j] * bf2f((u16)r[sc ][ci][j]);
                    o[j] += wv[6 + kx][j] * bf2f((u16)r[sp1][ci][j]);
                }
            }
            bf16x4 ov;
#pragma unroll
            for (int j = 0; j < 4; j++) {
                ov[j] = (short)f2bf(o[j]);
                as[j] += o[j];
                am[j] = fmaxf(am[j], o[j]);
            }
            *(bf16x4*)&xs[base + orow + (x0 + p) * CH] = ov;
        }
    }
#undef LOADROW

#pragma unroll
    for (int j = 0; j < 4; j++) {
        atomicAdd(&psum[(s * 8 + b) * CH + c0 + j], as[j]);
        atomicMax(&pmaxk[(s * 8 + b) * CH + c0 + j], fkey(am[j]));
    }
}

// gate softmax + channel conv1 gates + blended scale. grid (3, 8)
__global__ void k_scale(const float* __restrict__ psum, const u32* __restrict__ pmaxk,
                        const float* __restrict__ gate_w, const float* __restrict__ gate_b,
                        const float* __restrict__ ca_w, const float* __restrict__ ra_w,
                        float* __restrict__ scale) {
    int s = blockIdx.x, b = blockIdx.y;
    int tid = threadIdx.x;
    float npos = (s == 0) ? 4096.f : (s == 1) ? 1024.f : 256.f;
    __shared__ float pooled[CH];
    __shared__ float rl[4][2];
    float l0 = 0.f, l1 = 0.f;
#pragma unroll
    for (int j = 0; j < 3; j++) {
        int c = j * 256 + tid;
        size_t idx = ((size_t)s * 8 + b) * CH + c;
        float avg = psum[idx] / npos;
        float mxv = fkeyinv(pmaxk[idx]);
        pooled[c] = avg + mxv;
        l0 += avg * gate_w[c * 2 + 0];
        l1 += avg * gate_w[c * 2 + 1];
    }
    for (int off = 32; off; off >>= 1) {
        l0 += __shfl_down(l0, off);
        l1 += __shfl_down(l1, off);
    }
    int wave = tid >> 6, lane = tid & 63;
    if (lane == 0) { rl[wave][0] = l0; rl[wave][1] = l1; }
    __syncthreads();
    float L0 = rl[0][0] + rl[1][0] + rl[2][0] + rl[3][0] + gate_b[0];
    float L1 = rl[0][1] + rl[1][1] + rl[2][1] + rl[3][1] + gate_b[1];
    float mxl = fmaxf(L0, L1);
    float e0 = expf(L0 - mxl), e1 = expf(L1 - mxl);
    float g0 = e0 / (e0 + e1), g1 = e1 / (e0 + e1);
    float cw0 = ca_w[0], cw1 = ca_w[1], cw2 = ca_w[2];
    float rw0 = ra_w[0], rw1 = ra_w[1], rw2 = ra_w[2];
#pragma unroll
    for (int j = 0; j < 3; j++) {
        int c = j * 256 + tid;
        float pm = (c > 0)      ? pooled[c - 1] : 0.f;
        float pc = pooled[c];
        float pp = (c < CH - 1) ? pooled[c + 1] : 0.f;
        float cas = 1.f / (1.f + expf(-(cw0 * pm + cw1 * pc + cw2 * pp)));
        float ras = 1.f - 1.f / (1.f + expf(-(rw0 * pm + rw1 * pc + rw2 * pp)));
        scale[((size_t)s * 8 + b) * CH + c] = g0 * cas + g1 * ras;
    }
}

// streaming: xs <- bf16(GELU(xs * scale)) in place. grid-stride over c8-groups.
#define NG (M_ * (CH / 8))
__global__ void k_apply(u16* __restrict__ xs, const float* __restrict__ scale) {
    for (int gi = blockIdx.x * blockDim.x + threadIdx.x; gi < NG;
         gi += gridDim.x * blockDim.x) {
        int c8 = gi % 96;
        int tl = gi / 96;            // b*5376 + t
        int t = tl % NTOK, b = tl / NTOK;
        int s = (t < 4096) ? 0 : (t < 5120 ? 1 : 2);
        const float4* sp = (const float4*)&scale[((size_t)(s * 8 + b)) * CH + c8 * 8];
        float4 sc0 = sp[0], sc1 = sp[1];
        float scv[8] = {sc0.x, sc0.y, sc0.z, sc0.w, sc1.x, sc1.y, sc1.z, sc1.w};
        bf16x8 v = *(const bf16x8*)&xs[(size_t)gi * 8];
        bf16x8 o;
#pragma unroll
        for (int j = 0; j < 8; j++) {
            float f = bf2f((u16)v[j]) * scv[j];
            o[j] = (short)f2bf(gelu_exact(f));
        }
        *(bf16x8*)&xs[(size_t)gi * 8] = o;
    }
}

// ---------------------------------------------------------------- launch
extern "C" void kernel_launch(void* const* d_in, const int* in_sizes, int n_in,
                              void* d_out, int out_size, void* d_ws, size_t ws_size,
                              hipStream_t stream) {
    const float* x      = (const float*)d_in[0];
    const float* fc1_w  = (const float*)d_in[1];
    const float* fc1_b  = (const float*)d_in[2];
    const float* dw_w   = (const float*)d_in[3];
    const float* dw_b   = (const float*)d_in[4];
    const float* ca_w   = (const float*)d_in[5];
    const float* ra_w   = (const float*)d_in[6];
    const float* gate_w = (const float*)d_in[7];
    const float* gate_b = (const float*)d_in[8];
    const float* fc2_w  = (const float*)d_in[9];
    const float* fc2_b  = (const float*)d_in[10];

    char* ws = (char*)d_ws;
    u16*  hb    = (u16*)(ws);                    // 43008*768*2  = 66,060,288
    u16*  xs    = (u16*)(ws + 66060288);         // 43008*768*2  = 66,060,288
    u16*  w1T   = (u16*)(ws + 132120576);        // 768*384*2    =    589,824
    u16*  w2T   = (u16*)(ws + 132710400);        // 384*768*2    =    589,824
    float* psum = (float*)(ws + 133300224);      // 3*8*768*4    =     73,728
    u32*  pmaxk = (u32*)(ws + 133373952);        // 3*8*768*4    =     73,728
    float* scale= (float*)(ws + 133447680);      // 3*8*768*4    =     73,728

    // 0) zero the atomic accumulators (psum=0; pmaxk key 0 < key(any real))
    hipMemsetAsync((void*)psum, 0, 147456, stream);

    // 1) weight transpose+convert (1.2 MB total)
    k_cvt_wT<<<(CIN * CH + 255) / 256, 256, 0, stream>>>(fc1_w, w1T, CIN, CH);
    k_cvt_wT<<<(CIN * CH + 255) / 256, 256, 0, stream>>>(fc2_w, w2T, CH, CIN);

    // 2) fc1 (f32->bf16 packed-convert fused into A staging): x @ fc1_w -> h bf16
    gemm_fused<0, true><<<dim3(M_ / BM, CH / BN), 256, 0, stream>>>(
        (const void*)x, w1T, fc1_b, (void*)hb, M_, CH, CIN);

    // 3) depthwise conv (4x8 tiled register window) -> xs + atomic stats
    k_conv<<<dim3(168, 8), 192, 0, stream>>>(hb, dw_w, dw_b, xs, psum, pmaxk);

    // 4) per-(scale,b) gate/scale computation
    k_scale<<<dim3(3, 8), 256, 0, stream>>>(psum, pmaxk, gate_w, gate_b, ca_w, ra_w, scale);

    // 5) streaming scale + exact GELU, in place on xs
    k_apply<<<4096, 256, 0, stream>>>(xs, scale);

    // 6) fc2 (pure DMA staging, 2-phase): GELU'd xs @ fc2_w + bias -> out f32
    gemm_fused<2, false><<<dim3(M_ / BM, CIN / BN), 256, 0, stream>>>(
        (const void*)xs, w2T, fc2_b, d_out, M_, CIN, CH);
}

// Round 10
// 330.229 us; speedup vs baseline: 1.2513x; 1.1005x over previous
//
#include <hip/hip_runtime.h>
#include <hip/hip_bf16.h>
#include <math.h>

#define B_   8
#define NTOK 5376
#define CIN  384
#define CH   768
#define M_   (B_*NTOK)   // 43008

typedef unsigned short u16;
typedef unsigned int   u32;

using bf16x8 = __attribute__((ext_vector_type(8))) short;
using bf16x4 = __attribute__((ext_vector_type(4))) short;
using f32x4  = __attribute__((ext_vector_type(4))) float;

__device__ __forceinline__ u16 f2bf(float f) {
    union { float f; u32 u; } v; v.f = f;
    u32 r = v.u + 0x7fffu + ((v.u >> 16) & 1u);   // RNE (finite inputs)
    return (u16)(r >> 16);
}
__device__ __forceinline__ float bf2f(u16 u) {
    union { u32 u; float f; } v; v.u = ((u32)u) << 16;
    return v.f;
}
// monotonic order-preserving f32 <-> u32 key (for atomicMax); key(any real) > 0
__device__ __forceinline__ u32 fkey(float f) {
    union { float f; u32 u; } v; v.f = f;
    return (v.u & 0x80000000u) ? ~v.u : (v.u | 0x80000000u);
}
__device__ __forceinline__ float fkeyinv(u32 k) {
    union { u32 u; float f; } v;
    v.u = (k & 0x80000000u) ? (k ^ 0x80000000u) : ~k;
    return v.f;
}
__device__ __forceinline__ float gelu_exact(float f) {
    return 0.5f * f * (1.f + erff(f * 0.70710678118654752f));
}

// ---------------------------------------------------------------- converts
// src: (K, N) f32 row-major  ->  dst: (N, K) bf16 row-major
__global__ void k_cvt_wT(const float* __restrict__ w, u16* __restrict__ wT, int K, int N) {
    int i = blockIdx.x * blockDim.x + threadIdx.x;
    if (i >= N * K) return;
    int n = i / K, k = i % K;
    wT[i] = f2bf(w[k * N + n]);
}

// ---------------------------------------------------------------- GEMM
// C[M,N] = A[M,K] @ Bt[N,K]^T + bias. Single-buffer, 2 barriers/K-iter
// (measured best: implicit wave overlap across ~4 resident blocks).
//   AM==0: A is f32 -> reg-stage + v_cvt_pk_bf16_f32 convert + ds_write (fc1)
//   AM==2: A is bf16 -> global_load_lds DMA like B (fc2)
#define BM 128
#define BN 128
#define BK 64

template<int AM, bool OUT_BF16>
__launch_bounds__(256)
__global__ void gemm_fused(const void* __restrict__ Asrc, const u16* __restrict__ Bt,
                           const float* __restrict__ bias, void* __restrict__ Cout,
                           int M, int N, int K) {
    __shared__ __align__(16) u16 sA[BM * BK];
    __shared__ __align__(16) u16 sB[BN * BK];
    const int mt = blockIdx.x, nt = blockIdx.y;
    const int tid = threadIdx.x;
    const int wave = tid >> 6, lane = tid & 63;
    const int wm = wave >> 1, wn = wave & 1;
    const int row0 = mt * BM, col0 = nt * BN;
    const int lr = lane & 15, lk = lane >> 4;

    f32x4 acc[4][4];
#pragma unroll
    for (int m = 0; m < 4; m++)
#pragma unroll
        for (int n = 0; n < 4; n++) acc[m][n] = (f32x4){0.f, 0.f, 0.f, 0.f};

    const int KT = K / BK;
    for (int kt = 0; kt < KT; ++kt) {
        const int k0 = kt * BK;
        // ---- B tile (and A tile if AM==2): async DMA to LDS
#pragma unroll
        for (int it = 0; it < 4; ++it) {
            int g  = it * 256 + tid;
            int r  = g >> 3;
            int ks = g & 7;
            const u16* gB = Bt + (size_t)(col0 + r) * K + k0 + ks * 8;
            u16* lB = sB + (size_t)(it * 256 + wave * 64) * 8;   // wave-uniform base
            __builtin_amdgcn_global_load_lds(
                (const __attribute__((address_space(1))) u32*)(const void*)gB,
                (__attribute__((address_space(3))) u32*)(void*)lB, 16, 0, 0);
            if (AM == 2) {
                const u16* gA = (const u16*)Asrc + (size_t)(row0 + r) * K + k0 + ks * 8;
                u16* lA = sA + (size_t)(it * 256 + wave * 64) * 8;
                __builtin_amdgcn_global_load_lds(
                    (const __attribute__((address_space(1))) u32*)(const void*)gA,
                    (__attribute__((address_space(3))) u32*)(void*)lA, 16, 0, 0);
            }
        }
        // ---- A tile for AM==0: reg-stage f32 + packed convert + ds_write
        if (AM == 0) {
#pragma unroll
            for (int it = 0; it < 4; ++it) {
                int g  = it * 256 + tid;
                int r  = g >> 3;
                int ks = g & 7;
                const float* ga = (const float*)Asrc + (size_t)(row0 + r) * K + k0 + ks * 8;
                float4 a0 = ((const float4*)ga)[0];
                float4 a1 = ((const float4*)ga)[1];
                union { __hip_bfloat162 h2[4]; bf16x8 v; } o;
                o.h2[0] = __float22bfloat162_rn({a0.x, a0.y});   // v_cvt_pk_bf16_f32
                o.h2[1] = __float22bfloat162_rn({a0.z, a0.w});
                o.h2[2] = __float22bfloat162_rn({a1.x, a1.y});
                o.h2[3] = __float22bfloat162_rn({a1.z, a1.w});
                *(bf16x8*)&sA[(size_t)g * 8] = o.v;
            }
        }
        __syncthreads();   // drains lgkm (A ds_write) + vm (DMA)
#pragma unroll
        for (int kk = 0; kk < 2; ++kk) {
            bf16x8 af[4], bfr[4];
#pragma unroll
            for (int m = 0; m < 4; m++)
                af[m] = *(const bf16x8*)&sA[(wm * 64 + m * 16 + lr) * BK + kk * 32 + lk * 8];
#pragma unroll
            for (int n = 0; n < 4; n++)
                bfr[n] = *(const bf16x8*)&sB[(wn * 64 + n * 16 + lr) * BK + kk * 32 + lk * 8];
#pragma unroll
            for (int m = 0; m < 4; m++)
#pragma unroll
                for (int n = 0; n < 4; n++)
                    acc[m][n] = __builtin_amdgcn_mfma_f32_16x16x32_bf16(af[m], bfr[n], acc[m][n], 0, 0, 0);
        }
        __syncthreads();
    }

#pragma unroll
    for (int m = 0; m < 4; m++) {
#pragma unroll
        for (int n = 0; n < 4; n++) {
            int col = col0 + wn * 64 + n * 16 + lr;
            float bv = bias[col];
#pragma unroll
            for (int r = 0; r < 4; r++) {
                int row = row0 + wm * 64 + m * 16 + lk * 4 + r;
                float v = acc[m][n][r] + bv;
                if (OUT_BF16)
                    ((u16*)Cout)[(size_t)row * N + col] = f2bf(v);
                else
                    ((float*)Cout)[(size_t)row * N + col] = v;
            }
        }
    }
}

// ---------------------------------------------------------------- conv pass
// Measured-best geometry (round 4, 69 us): one block per (tile, b); tile = 8x8
// positions, 192 threads = 192 channel-quads, 8B bf16x4 loads.
// 3-row x 10-col circular register window (compile-time slots), fully unrolled.
// tiles: 0..63 -> s0 (8x8 grid), 64..79 -> s1 (4x4), 80..83 -> s2 (2x2)
__launch_bounds__(192)
__global__ void k_conv(const u16* __restrict__ h, const float* __restrict__ dw_w,
                       const float* __restrict__ dw_b, u16* __restrict__ xs,
                       float* __restrict__ psum, u32* __restrict__ pmaxk) {
    const int tile = blockIdx.x, b = blockIdx.y;
    int s, xt, yt, tokbase, LW;
    if (tile < 64)      { s = 0; xt = tile & 7;  yt = tile >> 3; tokbase = 0;    LW = 6; }
    else if (tile < 80) { int u = tile - 64; s = 1; xt = u & 3; yt = u >> 2; tokbase = 4096; LW = 5; }
    else                { int u = tile - 80; s = 2; xt = u & 1; yt = u >> 1; tokbase = 5120; LW = 4; }
    const int W = 1 << LW, H = W;
    const int x0 = xt * 8, y0 = yt * 8;
    const int c0 = threadIdx.x * 4;

    float wv[9][4], dwb[4];
#pragma unroll
    for (int j = 0; j < 4; j++) {
        dwb[j] = dw_b[c0 + j];
#pragma unroll
        for (int t = 0; t < 9; t++) wv[t][j] = dw_w[(c0 + j) * 9 + t];
    }

    const size_t base = ((size_t)(b * NTOK + tokbase)) * CH + c0;
    const bf16x4 z4 = (bf16x4){0, 0, 0, 0};
    bool colv[10];
    int coloff[10];
#pragma unroll
    for (int j = 0; j < 10; j++) {
        int xx = x0 - 1 + j;
        colv[j] = (xx >= 0) && (xx < W);
        coloff[j] = xx * CH;
    }

    bf16x4 r[3][10];

#define LOADROW(slot, yrow) {                                                   \
        int yr_ = (yrow);                                                       \
        bool rv_ = ((unsigned)yr_ < (unsigned)H);                               \
        int rb_ = yr_ * W * CH;                                                 \
        _Pragma("unroll")                                                       \
        for (int j = 0; j < 10; j++)                                            \
            r[slot][j] = (rv_ && colv[j]) ? *(const bf16x4*)&h[base + rb_ + coloff[j]] : z4; \
    }

    LOADROW(0, y0 - 1);
    LOADROW(1, y0);

    float as[4] = {0.f, 0.f, 0.f, 0.f};
    float am[4] = {-3.4e38f, -3.4e38f, -3.4e38f, -3.4e38f};

#pragma unroll
    for (int yy = 0; yy < 8; ++yy) {
        const int sm1 = yy % 3, sc = (yy + 1) % 3, sp1 = (yy + 2) % 3;
        LOADROW(sp1, y0 + yy + 1);
        const int orow = (y0 + yy) * W * CH;
#pragma unroll
        for (int p = 0; p < 8; ++p) {
            float o[4];
#pragma unroll
            for (int j = 0; j < 4; j++) o[j] = dwb[j];
#pragma unroll
            for (int kx = 0; kx < 3; ++kx) {
                const int ci = p + kx;
#pragma unroll
                for (int j = 0; j < 4; j++) {
                    o[j] += wv[0 + kx][j] * bf2f((u16)r[sm1][ci][j]);
                    o[j] += wv[3 + kx][j] * bf2f((u16)r[sc ][ci][j]);
                    o[j] += wv[6 + kx][j] * bf2f((u16)r[sp1][ci][j]);
                }
            }
            bf16x4 ov;
#pragma unroll
            for (int j = 0; j < 4; j++) {
                ov[j] = (short)f2bf(o[j]);
                as[j] += o[j];
                am[j] = fmaxf(am[j], o[j]);
            }
            *(bf16x4*)&xs[base + orow + (x0 + p) * CH] = ov;
        }
    }
#undef LOADROW

#pragma unroll
    for (int j = 0; j < 4; j++) {
        atomicAdd(&psum[(s * 8 + b) * CH + c0 + j], as[j]);
        atomicMax(&pmaxk[(s * 8 + b) * CH + c0 + j], fkey(am[j]));
    }
}

// gate softmax + channel conv1 gates + blended scale. grid (3, 8)
__global__ void k_scale(const float* __restrict__ psum, const u32* __restrict__ pmaxk,
                        const float* __restrict__ gate_w, const float* __restrict__ gate_b,
                        const float* __restrict__ ca_w, const float* __restrict__ ra_w,
                        float* __restrict__ scale) {
    int s = blockIdx.x, b = blockIdx.y;
    int tid = threadIdx.x;
    float npos = (s == 0) ? 4096.f : (s == 1) ? 1024.f : 256.f;
    __shared__ float pooled[CH];
    __shared__ float rl[4][2];
    float l0 = 0.f, l1 = 0.f;
#pragma unroll
    for (int j = 0; j < 3; j++) {
        int c = j * 256 + tid;
        size_t idx = ((size_t)s * 8 + b) * CH + c;
        float avg = psum[idx] / npos;
        float mxv = fkeyinv(pmaxk[idx]);
        pooled[c] = avg + mxv;
        l0 += avg * gate_w[c * 2 + 0];
        l1 += avg * gate_w[c * 2 + 1];
    }
    for (int off = 32; off; off >>= 1) {
        l0 += __shfl_down(l0, off);
        l1 += __shfl_down(l1, off);
    }
    int wave = tid >> 6, lane = tid & 63;
    if (lane == 0) { rl[wave][0] = l0; rl[wave][1] = l1; }
    __syncthreads();
    float L0 = rl[0][0] + rl[1][0] + rl[2][0] + rl[3][0] + gate_b[0];
    float L1 = rl[0][1] + rl[1][1] + rl[2][1] + rl[3][1] + gate_b[1];
    float mxl = fmaxf(L0, L1);
    float e0 = expf(L0 - mxl), e1 = expf(L1 - mxl);
    float g0 = e0 / (e0 + e1), g1 = e1 / (e0 + e1);
    float cw0 = ca_w[0], cw1 = ca_w[1], cw2 = ca_w[2];
    float rw0 = ra_w[0], rw1 = ra_w[1], rw2 = ra_w[2];
#pragma unroll
    for (int j = 0; j < 3; j++) {
        int c = j * 256 + tid;
        float pm = (c > 0)      ? pooled[c - 1] : 0.f;
        float pc = pooled[c];
        float pp = (c < CH - 1) ? pooled[c + 1] : 0.f;
        float cas = 1.f / (1.f + expf(-(cw0 * pm + cw1 * pc + cw2 * pp)));
        float ras = 1.f - 1.f / (1.f + expf(-(rw0 * pm + rw1 * pc + rw2 * pp)));
        scale[((size_t)s * 8 + b) * CH + c] = g0 * cas + g1 * ras;
    }
}

// streaming: xs <- bf16(GELU(xs * scale)) in place. grid-stride over c8-groups.
#define NG (M_ * (CH / 8))
__global__ void k_apply(u16* __restrict__ xs, const float* __restrict__ scale) {
    for (int gi = blockIdx.x * blockDim.x + threadIdx.x; gi < NG;
         gi += gridDim.x * blockDim.x) {
        int c8 = gi % 96;
        int tl = gi / 96;            // b*5376 + t
        int t = tl % NTOK, b = tl / NTOK;
        int s = (t < 4096) ? 0 : (t < 5120 ? 1 : 2);
        const float4* sp = (const float4*)&scale[((size_t)(s * 8 + b)) * CH + c8 * 8];
        float4 sc0 = sp[0], sc1 = sp[1];
        float scv[8] = {sc0.x, sc0.y, sc0.z, sc0.w, sc1.x, sc1.y, sc1.z, sc1.w};
        bf16x8 v = *(const bf16x8*)&xs[(size_t)gi * 8];
        bf16x8 o;
#pragma unroll
        for (int j = 0; j < 8; j++) {
            float f = bf2f((u16)v[j]) * scv[j];
            o[j] = (short)f2bf(gelu_exact(f));
        }
        *(bf16x8*)&xs[(size_t)gi * 8] = o;
    }
}

// ---------------------------------------------------------------- launch
extern "C" void kernel_launch(void* const* d_in, const int* in_sizes, int n_in,
                              void* d_out, int out_size, void* d_ws, size_t ws_size,
                              hipStream_t stream) {
    const float* x      = (const float*)d_in[0];
    const float* fc1_w  = (const float*)d_in[1];
    const float* fc1_b  = (const float*)d_in[2];
    const float* dw_w   = (const float*)d_in[3];
    const float* dw_b   = (const float*)d_in[4];
    const float* ca_w   = (const float*)d_in[5];
    const float* ra_w   = (const float*)d_in[6];
    const float* gate_w = (const float*)d_in[7];
    const float* gate_b = (const float*)d_in[8];
    const float* fc2_w  = (const float*)d_in[9];
    const float* fc2_b  = (const float*)d_in[10];

    char* ws = (char*)d_ws;
    u16*  hb    = (u16*)(ws);                    // 43008*768*2  = 66,060,288
    u16*  xs    = (u16*)(ws + 66060288);         // 43008*768*2  = 66,060,288
    u16*  w1T   = (u16*)(ws + 132120576);        // 768*384*2    =    589,824
    u16*  w2T   = (u16*)(ws + 132710400);        // 384*768*2    =    589,824
    float* psum = (float*)(ws + 133300224);      // 3*8*768*4    =     73,728
    u32*  pmaxk = (u32*)(ws + 133373952);        // 3*8*768*4    =     73,728
    float* scale= (float*)(ws + 133447680);      // 3*8*768*4    =     73,728

    // 0) zero the atomic accumulators (psum=0; pmaxk key 0 < key(any real))
    hipMemsetAsync((void*)psum, 0, 147456, stream);

    // 1) weight transpose+convert (1.2 MB total)
    k_cvt_wT<<<(CIN * CH + 255) / 256, 256, 0, stream>>>(fc1_w, w1T, CIN, CH);
    k_cvt_wT<<<(CIN * CH + 255) / 256, 256, 0, stream>>>(fc2_w, w2T, CH, CIN);

    // 2) fc1 (f32->bf16 packed-convert fused into A staging): x @ fc1_w -> h bf16
    gemm_fused<0, true><<<dim3(M_ / BM, CH / BN), 256, 0, stream>>>(
        (const void*)x, w1T, fc1_b, (void*)hb, M_, CH, CIN);

    // 3) depthwise conv (8x8 tiled register window, measured-best) -> xs + atomic stats
    k_conv<<<dim3(84, 8), 192, 0, stream>>>(hb, dw_w, dw_b, xs, psum, pmaxk);

    // 4) per-(scale,b) gate/scale computation
    k_scale<<<dim3(3, 8), 256, 0, stream>>>(psum, pmaxk, gate_w, gate_b, ca_w, ra_w, scale);

    // 5) streaming scale + exact GELU, in place on xs
    k_apply<<<4096, 256, 0, stream>>>(xs, scale);

    // 6) fc2 (pure DMA staging): GELU'd xs @ fc2_w + bias -> out f32
    gemm_fused<2, false><<<dim3(M_ / BM, CIN / BN), 256, 0, stream>>>(
        (const void*)xs, w2T, fc2_b, d_out, M_, CIN, CH);
}